// Round 4
// baseline (539.544 us; speedup 1.0000x reference)
//
#include <hip/hip_runtime.h>

// Problem constants (from reference)
#define BB   32
#define CC   64
#define HH   224
#define WW   224
#define H2   226
#define W2   226
#define HID  8

constexpr unsigned NPLANE = BB * CC;        // 2048 planes
constexpr unsigned XHW    = HH * WW;        // 50176 floats / x plane
constexpr unsigned HW2    = H2 * W2;        // 51076 floats / out plane
constexpr unsigned F4PP   = XHW / 4;        // 12544 aligned f4 / plane
constexpr unsigned NCOPYB = NPLANE * F4PP / 256;  // 100352 copy blocks
constexpr unsigned NBORD  = NPLANE * HH;    // 458752 threads per border
constexpr unsigned NBORDB = 4 * NBORD / 256;      // 7168 border blocks

typedef float f4v  __attribute__((ext_vector_type(4)));
typedef f4v  uf4 __attribute__((aligned(4)));   // dword-aligned vector store

// ---------------------------------------------------------------------------
// MLP: s[2][3] -> scalar. W layout: [w1 48][b1 8][w2 64][b2 8][w3 8][b3 1]
// ---------------------------------------------------------------------------
__device__ __forceinline__ float mlp_eval(const float s[2][3],
                                          const float* __restrict__ W) {
    const float* W1  = W;
    const float* B1  = W + 48;
    const float* W2m = W + 56;
    const float* B2  = W + 120;
    const float* W3  = W + 128;
    const float  b3  = W[136];
    float y1[HID];
#pragma unroll
    for (int h = 0; h < HID; ++h) {
        float a = B1[h];
#pragma unroll
        for (int r = 0; r < 2; ++r)
#pragma unroll
            for (int k = 0; k < 3; ++k)
                a = fmaf(s[r][k], W1[h * 6 + r * 3 + k], a);
        y1[h] = fmaxf(a, 0.f);
    }
    float y2[HID];
#pragma unroll
    for (int o = 0; o < HID; ++o) {
        float a = B2[o];
#pragma unroll
        for (int h = 0; h < HID; ++h) a = fmaf(y1[h], W2m[o * 8 + h], a);
        y2[o] = fmaxf(a, 0.f);
    }
    float a = b3;
#pragma unroll
    for (int h = 0; h < HID; ++h) a = fmaf(y2[h], W3[h], a);
    return fmaxf(a, 0.f);
}

// top/bottom MLP at border position l (r0 = 0 for top, 222 for bottom)
__device__ __forceinline__ float eval_tb(const float* __restrict__ xp,
                                         const float* __restrict__ W,
                                         unsigned l, unsigned r0) {
    float s[2][3];
#pragma unroll
    for (int r = 0; r < 2; ++r)
#pragma unroll
        for (int k = 0; k < 3; ++k) {
            unsigned xc = l + (unsigned)k - 1u;  // wrap-huge if OOB
            s[r][k] = (xc < (unsigned)WW) ? xp[(r0 + (unsigned)r) * WW + xc] : 0.f;
        }
    return mlp_eval(s, W);
}

#define LOADW(br, base)                                                  \
    if (t < 48u) wts[br][t] = base[0][t];                                \
    if (t < 64u) wts[br][56u + t] = base[2][t];                          \
    if (t < 8u) {                                                        \
        wts[br][48u + t]  = base[1][t];                                  \
        wts[br][120u + t] = base[3][t];                                  \
        wts[br][128u + t] = base[4][t];                                  \
    }                                                                    \
    if (t == 0u) wts[br][136] = base[5][0];

// ---------------------------------------------------------------------------
// Single fused kernel.
//  blocks [0, NBORDB): all 4 borders (incl. corners); read ONLY x + weights.
//  blocks [NBORDB, NBORDB+NCOPYB): interior copy, 1 aligned f4 load from x,
//    1 dword-aligned f4 store to out. Ring untouched by copy path.
// ---------------------------------------------------------------------------
__global__ __launch_bounds__(256) void fused_k(
    const float* __restrict__ x, float* __restrict__ out,
    const float* const* __restrict__ wp /* 24 pointers in d_ws */) {
    const unsigned t = threadIdx.x;

    if (blockIdx.x >= NBORDB) {
        // ---------------- interior copy ----------------
        const unsigned tid = (blockIdx.x - NBORDB) * 256u + t;
        const unsigned bc  = tid / F4PP;
        const unsigned f   = tid - bc * F4PP;
        const unsigned h   = f / 56u;
        const unsigned j   = f - h * 56u;
        const f4v v = *reinterpret_cast<const f4v*>(x + bc * XHW + h * WW + 4u * j);
        *reinterpret_cast<uf4*>(out + bc * HW2 + (h + 1u) * W2 + 1u + 4u * j) = v;
        return;
    }

    // ---------------- borders ----------------
    __shared__ float wts[4][137];
    {
        const float* const* w0 = wp;        // top: wp[0..5]
        const float* const* w1 = wp + 6;    // bottom
        const float* const* w2 = wp + 12;   // left
        const float* const* w3 = wp + 18;   // right
        LOADW(0, w0) LOADW(1, w1) LOADW(2, w2) LOADW(3, w3)
    }
    __syncthreads();

    const unsigned idx    = blockIdx.x * 256u + t;
    const unsigned border = idx / NBORD;          // 0=t 1=b 2=l 3=r
    const unsigned i2     = idx - border * NBORD;
    const unsigned bc     = i2 / (unsigned)HH;
    const unsigned l      = i2 - bc * (unsigned)HH;

    const float* xp = x + (size_t)bc * XHW;
    float*       op = out + (size_t)bc * HW2;

    if (border < 2u) {
        const bool top = (border == 0u);
        const float res = eval_tb(xp, top ? wts[0] : wts[1], l,
                                  top ? 0u : (unsigned)(HH - 2));
        op[(top ? 0u : (unsigned)(H2 - 1)) * W2 + l + 1u] = res;
        if (top && l == 0u) {  // corners stay zero
            op[0]                       = 0.f;
            op[W2 - 1]                  = 0.f;
            op[(H2 - 1u) * W2]          = 0.f;
            op[(H2 - 1u) * W2 + W2 - 1] = 0.f;
        }
    } else {
        const bool left   = (border == 2u);
        const unsigned cc0 = left ? 0u : (unsigned)(WW - 2);  // x cols
        const unsigned oc0 = left ? 1u : (unsigned)(W2 - 3);  // padded cols
        float s[2][3];
#pragma unroll
        for (int k = 0; k < 3; ++k) {
            const unsigned pr = l + (unsigned)k;  // padded row l..l+2
            float v0, v1;
            if (pr == 0u) {                  // top row: recompute 2 top-MLPs
                v0 = eval_tb(xp, wts[0], oc0 - 1u, 0u);
                v1 = eval_tb(xp, wts[0], oc0, 0u);
            } else if (pr == (unsigned)(H2 - 1)) {  // bottom row
                v0 = eval_tb(xp, wts[1], oc0 - 1u, (unsigned)(HH - 2));
                v1 = eval_tb(xp, wts[1], oc0, (unsigned)(HH - 2));
            } else {
                const float2 t2 = *reinterpret_cast<const float2*>(
                    xp + (pr - 1u) * (unsigned)WW + cc0);
                v0 = t2.x;
                v1 = t2.y;
            }
            s[0][k] = v0;
            s[1][k] = v1;
        }
        const float res = mlp_eval(s, left ? wts[2] : wts[3]);
        op[(l + 1u) * (unsigned)W2 + (left ? 0u : (unsigned)(W2 - 1))] = res;
    }
}

// ---------------------------------------------------------------------------
extern "C" void kernel_launch(void* const* d_in, const int* in_sizes, int n_in,
                              void* d_out, int out_size, void* d_ws,
                              size_t ws_size, hipStream_t stream) {
    const float* x = (const float*)d_in[0];
    float* out = (float*)d_out;

    // Stash the 24 weight pointers in workspace (device-visible array).
    // hipMemcpyAsync H2D of a small POD array is graph-capture legal.
    static const float* hptrs[24];
    for (int i = 0; i < 24; ++i) hptrs[i] = (const float*)d_in[1 + i];
    hipMemcpyAsync(d_ws, hptrs, sizeof(hptrs), hipMemcpyHostToDevice, stream);

    fused_k<<<dim3(NBORDB + NCOPYB), dim3(256), 0, stream>>>(
        x, out, (const float* const*)d_ws);
}

// Round 6
// 218.087 us; speedup vs baseline: 2.4740x; 2.4740x over previous
//
#include <hip/hip_runtime.h>

// Problem constants (from reference)
#define BB   32
#define CC   64
#define HH   224
#define WW   224
#define H2   226
#define W2   226
#define HID  8

constexpr unsigned NPLANE   = BB * CC;       // 2048 planes
constexpr unsigned XHW      = HH * WW;       // 50176 floats / x plane
constexpr unsigned HW2      = H2 * W2;       // 51076 floats / out plane
constexpr unsigned F4PLANE  = HW2 / 4;       // 12769 f4 / out plane
constexpr unsigned GPP      = 50;            // 50*256 = 12800 >= 12769
constexpr unsigned NBORD    = NPLANE * HH;   // 458752 per border
constexpr size_t   NXTOT    = (size_t)NPLANE * XHW;

// ---------------------------------------------------------------------------
// Kernel 1: padded copy via LDS realignment.
// Block (g,p): out plane p, flat out floats [g*1024, g*1024+1024).
// Stage the contiguous x span covering this range (aligned f4 loads), then
// each thread emits one aligned f4 store (ring positions -> 0).
// ---------------------------------------------------------------------------
__global__ __launch_bounds__(256) void pad_copy_k(const float* __restrict__ x,
                                                  float* __restrict__ out) {
    __shared__ __align__(16) float lds[1056];
    const unsigned t  = threadIdx.x;
    const unsigned g  = blockIdx.x;   // 0..49
    const unsigned p  = blockIdx.y;   // plane

    const unsigned o0 = g * 1024u;
    const unsigned h0 = o0 / 226u;
    const unsigned w0 = o0 - 226u * h0;
    int L0 = (int)(224u * h0 + w0) - 225 - 3;   // x offset of first needed elem, minus slop
    if (L0 < 0) L0 = 0;
    L0 &= ~3;

    // stage 264 aligned float4s = 1056 floats (covers span + alignment slop)
    const size_t pbase = (size_t)p * XHW;
    for (unsigned i = t; i < 264u; i += 256u) {
        size_t gi = pbase + (unsigned)L0 + 4u * i;
        if (gi > NXTOT - 4u) gi = NXTOT - 4u;   // clamp (garbage never consumed)
        const float4 v = *reinterpret_cast<const float4*>(x + gi);
        *reinterpret_cast<float4*>(&lds[4u * i]) = v;
    }
    __syncthreads();

    const unsigned f4 = g * 256u + t;
    if (f4 >= F4PLANE) return;
    const unsigned o = o0 + 4u * t;
    const unsigned h = o / 226u;
    const unsigned w = o - 226u * h;
    float vals[4];
#pragma unroll
    for (int e = 0; e < 4; ++e) {
        unsigned we = w + (unsigned)e;
        unsigned he = h;
        if (we >= 226u) { we -= 226u; ++he; }           // at most one row wrap
        const bool inter = ((he - 1u) < (unsigned)HH) & ((we - 1u) < (unsigned)WW);
        const int li = (int)(224u * he + we) - 225 - L0; // x offset - L0
        const unsigned lic = inter ? (unsigned)li : 0u;  // clamp before LDS read
        const float vv = lds[lic];
        vals[e] = inter ? vv : 0.f;                      // ring -> 0 (corners stay 0)
    }
    reinterpret_cast<float4*>(out + (size_t)p * HW2)[f4] =
        make_float4(vals[0], vals[1], vals[2], vals[3]);
}

// ---------------------------------------------------------------------------
// MLP: s[2][3] -> scalar. W layout: [w1 48][b1 8][w2 64][b2 8][w3 8][b3 1]
// ---------------------------------------------------------------------------
__device__ __forceinline__ float mlp_eval(const float s[2][3],
                                          const float* __restrict__ W) {
    const float* W1  = W;
    const float* B1  = W + 48;
    const float* W2m = W + 56;
    const float* B2  = W + 120;
    const float* W3  = W + 128;
    const float  b3  = W[136];
    float y1[HID];
#pragma unroll
    for (int h = 0; h < HID; ++h) {
        float a = B1[h];
#pragma unroll
        for (int r = 0; r < 2; ++r)
#pragma unroll
            for (int k = 0; k < 3; ++k)
                a = fmaf(s[r][k], W1[h * 6 + r * 3 + k], a);
        y1[h] = fmaxf(a, 0.f);
    }
    float y2[HID];
#pragma unroll
    for (int o = 0; o < HID; ++o) {
        float a = B2[o];
#pragma unroll
        for (int h = 0; h < HID; ++h) a = fmaf(y1[h], W2m[o * 8 + h], a);
        y2[o] = fmaxf(a, 0.f);
    }
    float a = b3;
#pragma unroll
    for (int h = 0; h < HID; ++h) a = fmaf(y2[h], W3[h], a);
    return fmaxf(a, 0.f);
}

__device__ __forceinline__ void load_wts(unsigned t, float* W,
                                         const float* w1, const float* b1,
                                         const float* w2, const float* b2,
                                         const float* w3, const float* b3) {
    if (t < 48u) W[t] = w1[t];
    if (t < 64u) W[56u + t] = w2[t];
    if (t < 8u) {
        W[48u + t]  = b1[t];
        W[120u + t] = b2[t];
        W[128u + t] = w3[t];
    }
    if (t == 0u) W[136] = b3[0];
}

// ---------------------------------------------------------------------------
// Kernel 2: top (blockIdx.y==0) / bottom (==1) borders. Reads x rows
// {0,1}/{222,223}; writes out rows 0/225, cols 1..224.
// ---------------------------------------------------------------------------
__global__ __launch_bounds__(256) void border_tb_k(
    const float* __restrict__ x, float* __restrict__ out,
    const float* tw1, const float* tb1, const float* tw2, const float* tb2,
    const float* tw3, const float* tb3,
    const float* bw1, const float* bb1, const float* bw2, const float* bb2,
    const float* bw3, const float* bb3) {
    const bool top = (blockIdx.y == 0);
    __shared__ float W[137];
    load_wts(threadIdx.x, W,
             top ? tw1 : bw1, top ? tb1 : bb1, top ? tw2 : bw2,
             top ? tb2 : bb2, top ? tw3 : bw3, top ? tb3 : bb3);
    __syncthreads();

    const unsigned gid = blockIdx.x * 256u + threadIdx.x;
    const unsigned l   = gid % (unsigned)HH;
    const unsigned bc  = gid / (unsigned)HH;

    const unsigned r0 = top ? 0u : (unsigned)(HH - 2);
    float s[2][3];
#pragma unroll
    for (int r = 0; r < 2; ++r)
#pragma unroll
        for (int k = 0; k < 3; ++k) {
            unsigned xc = l + (unsigned)k - 1u;  // wrap-huge if OOB
            s[r][k] = (xc < (unsigned)WW)
                          ? x[bc * XHW + (r0 + (unsigned)r) * (unsigned)WW + xc]
                          : 0.f;
        }
    const float res = mlp_eval(s, W);
    const unsigned orow = top ? 0u : (unsigned)(H2 - 1);
    out[bc * HW2 + orow * (unsigned)W2 + (l + 1u)] = res;
}

// ---------------------------------------------------------------------------
// Kernel 3: left (blockIdx.y==0) / right (==1) borders. Interior rows from x
// (aligned float2 at cols {0,1}/{222,223}); padded rows 0/225 read tb results
// from out. Writes cols 0/225, rows 1..224.
// ---------------------------------------------------------------------------
__global__ __launch_bounds__(256) void border_lr_k(
    const float* __restrict__ x, float* __restrict__ out,
    const float* lw1, const float* lb1, const float* lw2, const float* lb2,
    const float* lw3, const float* lb3,
    const float* rw1, const float* rb1, const float* rw2, const float* rb2,
    const float* rw3, const float* rb3) {
    const bool left = (blockIdx.y == 0);
    __shared__ float W[137];
    load_wts(threadIdx.x, W,
             left ? lw1 : rw1, left ? lb1 : rb1, left ? lw2 : rw2,
             left ? lb2 : rb2, left ? lw3 : rw3, left ? lb3 : rb3);
    __syncthreads();

    const unsigned gid = blockIdx.x * 256u + threadIdx.x;
    const unsigned l   = gid % (unsigned)HH;  // writes padded row l+1
    const unsigned bc  = gid / (unsigned)HH;

    const unsigned cc0 = left ? 0u : (unsigned)(WW - 2);  // x col base
    const unsigned oc0 = left ? 1u : (unsigned)(W2 - 3);  // out col base (rows 0/225)
    float s[2][3];
#pragma unroll
    for (int k = 0; k < 3; ++k) {
        const unsigned pr = l + (unsigned)k;  // padded row l..l+2
        float v0, v1;
        if (pr == 0u) {
            v0 = out[bc * HW2 + oc0];
            v1 = out[bc * HW2 + oc0 + 1u];
        } else if (pr == (unsigned)(H2 - 1)) {
            v0 = out[bc * HW2 + (unsigned)(H2 - 1) * W2 + oc0];
            v1 = out[bc * HW2 + (unsigned)(H2 - 1) * W2 + oc0 + 1u];
        } else {
            const float2 t2 = *reinterpret_cast<const float2*>(
                x + bc * XHW + (pr - 1u) * (unsigned)WW + cc0);
            v0 = t2.x;
            v1 = t2.y;
        }
        s[0][k] = v0;
        s[1][k] = v1;
    }
    const float res = mlp_eval(s, W);
    out[bc * HW2 + (l + 1u) * (unsigned)W2 + (left ? 0u : (unsigned)(W2 - 1))] = res;
}

// ---------------------------------------------------------------------------
extern "C" void kernel_launch(void* const* d_in, const int* in_sizes, int n_in,
                              void* d_out, int out_size, void* d_ws,
                              size_t ws_size, hipStream_t stream) {
    const float* x = (const float*)d_in[0];
    const float* w[24];
    for (int i = 0; i < 24; ++i) w[i] = (const float*)d_in[1 + i];
    float* out = (float*)d_out;

    // 1) padded copy (interior + zero ring; corners final)
    pad_copy_k<<<dim3(GPP, NPLANE), dim3(256), 0, stream>>>(x, out);

    // 2) top + bottom borders (read x only; write rows 0/225 cols 1..224)
    border_tb_k<<<dim3(NBORD / 256u, 2), dim3(256), 0, stream>>>(
        x, out, w[0], w[1], w[2], w[3], w[4], w[5],
        w[6], w[7], w[8], w[9], w[10], w[11]);

    // 3) left + right borders (read x cols + tb rows; write cols 0/225)
    border_lr_k<<<dim3(NBORD / 256u, 2), dim3(256), 0, stream>>>(
        x, out, w[12], w[13], w[14], w[15], w[16], w[17],
        w[18], w[19], w[20], w[21], w[22], w[23]);
}